// Round 1
// baseline (952.881 us; speedup 1.0000x reference)
//
#include <hip/hip_runtime.h>
#include <hip/hip_bf16.h>
#include <math.h>

#define NN 65536
#define EE 1048576
#define ET (EE + NN)      // 1114112 edges incl. self loops
#define NG 512

__device__ __constant__ const float BNS = 0.9999950000374997f; // 1/sqrt(1+1e-5)

// ---------------- CSR build ----------------

__global__ __launch_bounds__(256) void hist_kernel(const int* __restrict__ ei,
                                                   int* __restrict__ counts) {
  int i = blockIdx.x * 256 + threadIdx.x;
  if (i < ET) {
    int d = (i < EE) ? ei[EE + i] : (i - EE);
    atomicAdd(&counts[d], 1);
  }
}

// single-block exclusive scan; optionally rewrites counts[] into a cursor copy
__global__ __launch_bounds__(1024) void scan_kernel(int* __restrict__ counts,
                                                    int* __restrict__ off,
                                                    int n, int writeCursor) {
  __shared__ int sums[1024];
  int t = threadIdx.x;
  int chunk = (n + 1023) >> 10;
  int b0 = t * chunk;
  int b1 = min(b0 + chunk, n);
  int s = 0;
  for (int i = b0; i < b1; ++i) s += counts[i];
  sums[t] = s;
  __syncthreads();
  for (int d = 1; d < 1024; d <<= 1) {
    int v = (t >= d) ? sums[t - d] : 0;
    __syncthreads();
    sums[t] += v;
    __syncthreads();
  }
  int run = (t == 0) ? 0 : sums[t - 1];
  for (int i = b0; i < b1; ++i) {
    int c = counts[i];
    off[i] = run;
    if (writeCursor) counts[i] = run;  // counts becomes the scatter cursor
    run += c;
  }
  if (b1 == n && b0 <= n) off[n] = run;
}

__global__ __launch_bounds__(256) void scatter_kernel(const int* __restrict__ ei,
                                                      int* __restrict__ cursor,
                                                      int* __restrict__ csr_src) {
  int i = blockIdx.x * 256 + threadIdx.x;
  if (i < ET) {
    int d, s;
    if (i < EE) { d = ei[EE + i]; s = ei[i]; }
    else        { d = i - EE;     s = d;     }
    int pos = atomicAdd(&cursor[d], 1);
    csr_src[pos] = s;
  }
}

__global__ __launch_bounds__(256) void ghist_kernel(const int* __restrict__ batch,
                                                    int* __restrict__ gcnt) {
  int i = blockIdx.x * 256 + threadIdx.x;
  if (i < NN) atomicAdd(&gcnt[batch[i]], 1);
}

// ---------------- GEMM: xl = h@Wl, xr = h@Wr ----------------
// thread -> (8 rows, 1 col j). x rows via wave-broadcast float4 loads,
// W via coalesced (L2-cached) loads.

template <int FIN, int FOUT>
__global__ __launch_bounds__(256) void gemm_xlr(const float* __restrict__ hin,
                                                const float* __restrict__ Wl,
                                                const float* __restrict__ Wr,
                                                float* __restrict__ xl,
                                                float* __restrict__ xr) {
  int gt = blockIdx.x * 256 + threadIdx.x;
  int j = gt % FOUT;
  int rb = (gt / FOUT) * 8;
  if (rb >= NN) return;
  float accl[8] = {0, 0, 0, 0, 0, 0, 0, 0};
  float accr[8] = {0, 0, 0, 0, 0, 0, 0, 0};
  for (int k = 0; k < FIN; k += 4) {
    float4 xv[8];
#pragma unroll
    for (int r = 0; r < 8; ++r)
      xv[r] = *reinterpret_cast<const float4*>(&hin[(rb + r) * FIN + k]);
#pragma unroll
    for (int kk = 0; kk < 4; ++kk) {
      float wl = Wl[(k + kk) * FOUT + j];
      float wr = Wr[(k + kk) * FOUT + j];
#pragma unroll
      for (int r = 0; r < 8; ++r) {
        float xs = (kk == 0) ? xv[r].x : (kk == 1) ? xv[r].y : (kk == 2) ? xv[r].z : xv[r].w;
        accl[r] = fmaf(xs, wl, accl[r]);
        accr[r] = fmaf(xs, wr, accr[r]);
      }
    }
  }
#pragma unroll
  for (int r = 0; r < 8; ++r) {
    xl[(rb + r) * FOUT + j] = accl[r];
    xr[(rb + r) * FOUT + j] = accr[r];
  }
}

// ---------------- edge aggregation (online segment softmax) ----------------
// GROUP = FOUT/4 lanes own one dst node; float4 per lane; shfl-reduce scores;
// online-softmax accumulate; epilogue fuses +b, ReLU, BN-eval.

template <int FOUT>
__global__ __launch_bounds__(256) void edge_kernel(
    const float4* __restrict__ xl, const float4* __restrict__ xr,
    const int* __restrict__ csr_off, const int* __restrict__ csr_src,
    const float* __restrict__ a, const float* __restrict__ b,
    const float* __restrict__ gam, const float* __restrict__ bet,
    float4* __restrict__ hout) {
  constexpr int GROUP = FOUT / 4;   // 32 / 16 / 8
  constexpr int GPB = 256 / GROUP;  // 8 / 16 / 32
  int gid = blockIdx.x * GPB + threadIdx.x / GROUP;
  int lane = threadIdx.x % GROUP;
  if (gid >= NN) return;
  constexpr int F4 = FOUT / 4;

  float4 xrv = xr[gid * F4 + lane];
  float4 av = reinterpret_cast<const float4*>(a)[lane];
  int beg = csr_off[gid], end = csr_off[gid + 1];

  float m = -INFINITY, den = 0.f;
  float4 acc = {0.f, 0.f, 0.f, 0.f};
  for (int i = beg; i < end; ++i) {
    int s = csr_src[i];
    float4 xv = xl[s * F4 + lane];
    float zx = xv.x + xrv.x; zx = zx > 0.f ? zx : 0.2f * zx;
    float zy = xv.y + xrv.y; zy = zy > 0.f ? zy : 0.2f * zy;
    float zz = xv.z + xrv.z; zz = zz > 0.f ? zz : 0.2f * zz;
    float zw = xv.w + xrv.w; zw = zw > 0.f ? zw : 0.2f * zw;
    float sc = zx * av.x + zy * av.y + zz * av.z + zw * av.w;
#pragma unroll
    for (int w = GROUP >> 1; w >= 1; w >>= 1) sc += __shfl_xor(sc, w, GROUP);
    float mn = fmaxf(m, sc);
    float scale = __expf(m - mn);   // exp(-inf)=0 on first edge
    float p = __expf(sc - mn);
    den = den * scale + p;
    acc.x = acc.x * scale + p * xv.x;
    acc.y = acc.y * scale + p * xv.y;
    acc.z = acc.z * scale + p * xv.z;
    acc.w = acc.w * scale + p * xv.w;
    m = mn;
  }
  float inv = 1.f / den;  // den >= 1 (self loop guarantees a max edge)
  float4 bv = reinterpret_cast<const float4*>(b)[lane];
  float4 gv = reinterpret_cast<const float4*>(gam)[lane];
  float4 ev = reinterpret_cast<const float4*>(bet)[lane];
  float4 o;
  o.x = fmaxf(acc.x * inv + bv.x, 0.f) * (gv.x * BNS) + ev.x;
  o.y = fmaxf(acc.y * inv + bv.y, 0.f) * (gv.y * BNS) + ev.y;
  o.z = fmaxf(acc.z * inv + bv.z, 0.f) * (gv.z * BNS) + ev.z;
  o.w = fmaxf(acc.w * inv + bv.w, 0.f) * (gv.w * BNS) + ev.w;
  hout[gid * F4 + lane] = o;
}

// ---------------- pooling (segment sum over sorted batch) ----------------

template <int FOUT>
__global__ __launch_bounds__(64) void pool_kernel(const float* __restrict__ h,
                                                  const int* __restrict__ goff,
                                                  float* __restrict__ pooled,
                                                  int colbase, int colbase2) {
  int g = blockIdx.x;
  int t = threadIdx.x;
  constexpr int V = (FOUT + 63) / 64;
  float acc[V];
#pragma unroll
  for (int v = 0; v < V; ++v) acc[v] = 0.f;
  int b0 = goff[g], b1 = goff[g + 1];
  for (int n = b0; n < b1; ++n) {
#pragma unroll
    for (int v = 0; v < V; ++v) {
      int f = t + v * 64;
      if (f < FOUT) acc[v] += h[n * FOUT + f];
    }
  }
#pragma unroll
  for (int v = 0; v < V; ++v) {
    int f = t + v * 64;
    if (f < FOUT) {
      pooled[g * 256 + colbase + f] = acc[v];
      if (colbase2 >= 0) pooled[g * 256 + colbase2 + f] = acc[v];
    }
  }
}

// ---------------- MLP head + outputs ----------------

__global__ __launch_bounds__(128) void mlp_kernel(
    const float* __restrict__ pooled, const float* __restrict__ W1,
    const float* __restrict__ b1, const float* __restrict__ g5,
    const float* __restrict__ be5, const float* __restrict__ W2,
    const float* __restrict__ b2, float* __restrict__ out) {
  __shared__ float p[256];
  __shared__ float hid[128];
  __shared__ float lg[16];
  int g = blockIdx.x, t = threadIdx.x;
  p[t] = pooled[g * 256 + t];
  p[t + 128] = pooled[g * 256 + 128 + t];
  __syncthreads();
  float acc = b1[t];
  for (int k = 0; k < 256; ++k) acc = fmaf(p[k], W1[k * 128 + t], acc);
  acc = fmaxf(acc, 0.f) * (g5[t] * BNS) + be5[t];
  hid[t] = acc;
  __syncthreads();
  if (t < 16) {
    float l = b2[t];
    for (int k = 0; k < 128; ++k) l = fmaf(hid[k], W2[k * 16 + t], l);
    lg[t] = l;
  }
  __syncthreads();
  if (t < 16) {
    float l = lg[t];
    float m = lg[0];
    for (int k = 1; k < 16; ++k) m = fmaxf(m, lg[k]);
    float se = 0.f;
    for (int k = 0; k < 16; ++k) se += __expf(lg[k] - m);
    out[g * 16 + t] = 1.f / (1.f + __expf(-l));                 // sigmoid
    out[NG * 16 + g * 16 + t] = l - m - __logf(se);             // log_softmax
  }
}

// ---------------- launch ----------------

extern "C" void kernel_launch(void* const* d_in, const int* in_sizes, int n_in,
                              void* d_out, int out_size, void* d_ws, size_t ws_size,
                              hipStream_t stream) {
  const float* x = (const float*)d_in[0];
  const int* ei = (const int*)d_in[1];
  const int* batch = (const int*)d_in[2];
  const float* Wl1 = (const float*)d_in[4];
  const float* Wr1 = (const float*)d_in[5];
  const float* a1 = (const float*)d_in[6];
  const float* b1 = (const float*)d_in[7];
  const float* g1 = (const float*)d_in[8];
  const float* be1 = (const float*)d_in[9];
  const float* Wl2 = (const float*)d_in[10];
  const float* Wr2 = (const float*)d_in[11];
  const float* a2 = (const float*)d_in[12];
  const float* b2 = (const float*)d_in[13];
  const float* g2 = (const float*)d_in[14];
  const float* be2 = (const float*)d_in[15];
  const float* Wl3 = (const float*)d_in[16];
  const float* Wr3 = (const float*)d_in[17];
  const float* a3 = (const float*)d_in[18];
  const float* b3 = (const float*)d_in[19];
  const float* g3 = (const float*)d_in[20];
  const float* be3 = (const float*)d_in[21];
  // layer 4 (d_in[22..27]) is dead in the reference (h4 = h3) — skipped.
  const float* lin1_W = (const float*)d_in[28];
  const float* lin1_b = (const float*)d_in[29];
  const float* g5 = (const float*)d_in[30];
  const float* be5 = (const float*)d_in[31];
  const float* lin2_W = (const float*)d_in[32];
  const float* lin2_b = (const float*)d_in[33];
  float* out = (float*)d_out;

  // workspace carve (all 16B-aligned chunks)
  char* w = (char*)d_ws;
  float* xl = (float*)w;      w += (size_t)NN * 128 * 4;   // 32 MB
  float* xr = (float*)w;      w += (size_t)NN * 128 * 4;   // 32 MB
  float* h = (float*)w;       w += (size_t)NN * 128 * 4;   // 32 MB
  int* counts = (int*)w;      w += (size_t)NN * 4;          // doubles as cursor
  int* csr_off = (int*)w;     w += (size_t)(NN + 4) * 4;
  int* csr_src = (int*)w;     w += (size_t)ET * 4;
  int* gcnt = (int*)w;        w += (size_t)NG * 4;
  int* goff = (int*)w;        w += (size_t)(NG + 4) * 4;
  float* pooled = (float*)w;  w += (size_t)NG * 256 * 4;

  hipMemsetAsync(counts, 0, (size_t)NN * 4, stream);
  hipMemsetAsync(gcnt, 0, (size_t)NG * 4, stream);

  hist_kernel<<<ET / 256, 256, 0, stream>>>(ei, counts);
  scan_kernel<<<1, 1024, 0, stream>>>(counts, csr_off, NN, 1);
  scatter_kernel<<<ET / 256, 256, 0, stream>>>(ei, counts, csr_src);
  ghist_kernel<<<NN / 256, 256, 0, stream>>>(batch, gcnt);
  scan_kernel<<<1, 1024, 0, stream>>>(gcnt, goff, NG, 0);

  // ---- layer 1: 128 -> 128
  gemm_xlr<128, 128><<<(NN / 8) * 128 / 256, 256, 0, stream>>>(x, Wl1, Wr1, xl, xr);
  edge_kernel<128><<<NN / 8, 256, 0, stream>>>((const float4*)xl, (const float4*)xr,
                                               csr_off, csr_src, a1, b1, g1, be1,
                                               (float4*)h);
  pool_kernel<128><<<NG, 64, 0, stream>>>(h, goff, pooled, 0, -1);

  // ---- layer 2: 128 -> 64
  gemm_xlr<128, 64><<<(NN / 8) * 64 / 256, 256, 0, stream>>>(h, Wl2, Wr2, xl, xr);
  edge_kernel<64><<<NN / 16, 256, 0, stream>>>((const float4*)xl, (const float4*)xr,
                                               csr_off, csr_src, a2, b2, g2, be2,
                                               (float4*)h);
  pool_kernel<64><<<NG, 64, 0, stream>>>(h, goff, pooled, 128, -1);

  // ---- layer 3: 64 -> 32
  gemm_xlr<64, 32><<<(NN / 8) * 32 / 256, 256, 0, stream>>>(h, Wl3, Wr3, xl, xr);
  edge_kernel<32><<<NN / 32, 256, 0, stream>>>((const float4*)xl, (const float4*)xr,
                                               csr_off, csr_src, a3, b3, g3, be3,
                                               (float4*)h);
  pool_kernel<32><<<NG, 64, 0, stream>>>(h, goff, pooled, 192, 224);

  // ---- MLP head
  mlp_kernel<<<NG, 128, 0, stream>>>(pooled, lin1_W, lin1_b, g5, be5, lin2_W,
                                     lin2_b, out);
}

// Round 2
// 584.707 us; speedup vs baseline: 1.6297x; 1.6297x over previous
//
#include <hip/hip_runtime.h>
#include <hip/hip_bf16.h>
#include <math.h>

#define NN 65536
#define EE 1048576
#define ET (EE + NN)      // 1114112 edges incl. self loops
#define NG 512

typedef __attribute__((ext_vector_type(8))) short bf16x8;
typedef __attribute__((ext_vector_type(4))) float f32x4;

__device__ __constant__ const float BNS = 0.9999950000374997f; // 1/sqrt(1+1e-5)

// ---------------- bf16 helpers ----------------
__device__ inline float lo_bf(uint u) { union { uint i; float f; } v; v.i = u << 16; return v.f; }
__device__ inline float hi_bf(uint u) { union { uint i; float f; } v; v.i = u & 0xFFFF0000u; return v.f; }
__device__ inline uint f2bf(float f) {
  union { float f; uint i; } v; v.f = f;
  uint r = v.i + 0x7FFFu + ((v.i >> 16) & 1u);  // RTNE
  return r >> 16;
}
__device__ inline uint pack_bf2(float a, float b) { return f2bf(a) | (f2bf(b) << 16); }
__device__ inline void cvt8(uint4 v, float* o) {
  o[0] = lo_bf(v.x); o[1] = hi_bf(v.x); o[2] = lo_bf(v.y); o[3] = hi_bf(v.y);
  o[4] = lo_bf(v.z); o[5] = hi_bf(v.z); o[6] = lo_bf(v.w); o[7] = hi_bf(v.w);
}

// ---------------- CSR build ----------------

__global__ __launch_bounds__(256) void hist_kernel(const int* __restrict__ ei,
                                                   int* __restrict__ counts) {
  int i = blockIdx.x * 256 + threadIdx.x;
  if (i < ET) {
    int d = (i < EE) ? ei[EE + i] : (i - EE);
    atomicAdd(&counts[d], 1);
  }
}

__global__ __launch_bounds__(1024) void scan_kernel(int* __restrict__ counts,
                                                    int* __restrict__ off,
                                                    int n, int writeCursor) {
  __shared__ int sums[1024];
  int t = threadIdx.x;
  int chunk = (n + 1023) >> 10;
  int b0 = t * chunk;
  int b1 = min(b0 + chunk, n);
  int s = 0;
  for (int i = b0; i < b1; ++i) s += counts[i];
  sums[t] = s;
  __syncthreads();
  for (int d = 1; d < 1024; d <<= 1) {
    int v = (t >= d) ? sums[t - d] : 0;
    __syncthreads();
    sums[t] += v;
    __syncthreads();
  }
  int run = (t == 0) ? 0 : sums[t - 1];
  for (int i = b0; i < b1; ++i) {
    int c = counts[i];
    off[i] = run;
    if (writeCursor) counts[i] = run;
    run += c;
  }
  if (b1 == n && b0 <= n) off[n] = run;
}

__global__ __launch_bounds__(256) void scatter_kernel(const int* __restrict__ ei,
                                                      int* __restrict__ cursor,
                                                      int* __restrict__ csr_src) {
  int i = blockIdx.x * 256 + threadIdx.x;
  if (i < ET) {
    int d, s;
    if (i < EE) { d = ei[EE + i]; s = ei[i]; }
    else        { d = i - EE;     s = d;     }
    int pos = atomicAdd(&cursor[d], 1);
    csr_src[pos] = s;
  }
}

__global__ __launch_bounds__(256) void ghist_kernel(const int* __restrict__ batch,
                                                    int* __restrict__ gcnt) {
  int i = blockIdx.x * 256 + threadIdx.x;
  if (i < NN) atomicAdd(&gcnt[batch[i]], 1);
}

// ---------------- input convert & weight pack ----------------

__global__ __launch_bounds__(256) void cvt_kernel(const float* __restrict__ x,
                                                  ushort* __restrict__ xb) {
  int i = blockIdx.x * 256 + threadIdx.x;   // 4 floats per thread
  float4 v = ((const float4*)x)[i];
  uint2 o; o.x = pack_bf2(v.x, v.y); o.y = pack_bf2(v.z, v.w);
  ((uint2*)xb)[i] = o;
}

// pack W [FIN x FOUT] f32 into MFMA A-fragment layout (W^T tiles), bf16
__global__ __launch_bounds__(256) void pack_kernel(
    const float* __restrict__ Wl1, const float* __restrict__ Wr1,
    const float* __restrict__ Wl2, const float* __restrict__ Wr2,
    const float* __restrict__ Wl3, const float* __restrict__ Wr3,
    ushort* __restrict__ P1l, ushort* __restrict__ P1r,
    ushort* __restrict__ P2l, ushort* __restrict__ P2r,
    ushort* __restrict__ P3l, ushort* __restrict__ P3r) {
  int b = blockIdx.x;
  const float* W; ushort* P; int FIN, FOUT, base;
  if (b < 8)       { W = Wl1; P = P1l; FIN = 128; FOUT = 128; base = b; }
  else if (b < 16) { W = Wr1; P = P1r; FIN = 128; FOUT = 128; base = b - 8; }
  else if (b < 20) { W = Wl2; P = P2l; FIN = 128; FOUT = 64;  base = b - 16; }
  else if (b < 24) { W = Wr2; P = P2r; FIN = 128; FOUT = 64;  base = b - 20; }
  else if (b < 25) { W = Wl3; P = P3l; FIN = 64;  FOUT = 32;  base = 0; }
  else             { W = Wr3; P = P3r; FIN = 64;  FOUT = 32;  base = 0; }
  int tid = base * 256 + threadIdx.x;
  int KS = FIN / 32, NF = FOUT / 16;
  if (tid >= NF * KS * 64) return;
  int lane = tid & 63, t = (tid >> 6) % KS, cf = (tid >> 6) / KS;
  int f = cf * 16 + (lane & 15);
  int k0 = t * 32 + (lane >> 4) * 8;
  uint4 v;
  v.x = pack_bf2(W[(k0 + 0) * FOUT + f], W[(k0 + 1) * FOUT + f]);
  v.y = pack_bf2(W[(k0 + 2) * FOUT + f], W[(k0 + 3) * FOUT + f]);
  v.z = pack_bf2(W[(k0 + 4) * FOUT + f], W[(k0 + 5) * FOUT + f]);
  v.w = pack_bf2(W[(k0 + 6) * FOUT + f], W[(k0 + 7) * FOUT + f]);
  ((uint4*)P)[tid] = v;
}

// ---------------- MFMA GEMM: xl = xin@Wl, xr = xin@Wr (all bf16) ----------------
// Swapped operands: D[F][M] tile = Wt_frag[16F x 32K] * Xt_frag[32K x 16M].
// Lane l: M-index = mb + (l&15), F-index = F0 + (l>>4)*4 + r.

template <int FIN, int FOUT, int TILES>
__global__ __launch_bounds__(256) void gemm_mfma(
    const ushort* __restrict__ xin, const ushort* __restrict__ Wlp,
    const ushort* __restrict__ Wrp, ushort* __restrict__ xl,
    ushort* __restrict__ xr) {
  constexpr int KS = FIN / 32;
  constexpr int NF = FOUT / 16;
  constexpr int FW = (NF < 4) ? NF : 4;   // waves covering F
  constexpr int CFW = NF / FW;            // F-frags per wave
  constexpr int NW = 4 / FW;              // node groups per block
  const int w = threadIdx.x >> 6, lane = threadIdx.x & 63;
  const int fseg = w % FW, ng = w / FW;
  const int l15 = lane & 15, lhi = lane >> 4;

  bf16x8 wfl[CFW][KS], wfr[CFW][KS];
#pragma unroll
  for (int c = 0; c < CFW; ++c)
#pragma unroll
    for (int t = 0; t < KS; ++t) {
      int idx = ((fseg * CFW + c) * KS + t) * 64 + lane;
      wfl[c][t] = ((const bf16x8*)Wlp)[idx];
      wfr[c][t] = ((const bf16x8*)Wrp)[idx];
    }

  size_t tile0 = ((size_t)blockIdx.x * NW + ng) * TILES;
  for (int it = 0; it < TILES; ++it) {
    int mb = (int)(tile0 + it) * 16;
    const bf16x8* xrow = (const bf16x8*)(xin + (size_t)(mb + l15) * FIN);
    bf16x8 bx[KS];
#pragma unroll
    for (int t = 0; t < KS; ++t) bx[t] = xrow[t * 4 + lhi];  // k = t*32 + lhi*8
    f32x4 accl[CFW], accr[CFW];
#pragma unroll
    for (int c = 0; c < CFW; ++c) {
      accl[c] = (f32x4){0.f, 0.f, 0.f, 0.f};
      accr[c] = (f32x4){0.f, 0.f, 0.f, 0.f};
    }
#pragma unroll
    for (int t = 0; t < KS; ++t)
#pragma unroll
      for (int c = 0; c < CFW; ++c) {
        accl[c] = __builtin_amdgcn_mfma_f32_16x16x32_bf16(wfl[c][t], bx[t], accl[c], 0, 0, 0);
        accr[c] = __builtin_amdgcn_mfma_f32_16x16x32_bf16(wfr[c][t], bx[t], accr[c], 0, 0, 0);
      }
#pragma unroll
    for (int c = 0; c < CFW; ++c) {
      int f0 = (fseg * CFW + c) * 16 + lhi * 4;
      size_t o = (size_t)(mb + l15) * FOUT + f0;
      uint2 vl; vl.x = pack_bf2(accl[c][0], accl[c][1]); vl.y = pack_bf2(accl[c][2], accl[c][3]);
      *(uint2*)(xl + o) = vl;
      uint2 vr; vr.x = pack_bf2(accr[c][0], accr[c][1]); vr.y = pack_bf2(accr[c][2], accr[c][3]);
      *(uint2*)(xr + o) = vr;
    }
  }
}

// ---------------- edge aggregation (online segment softmax, bf16 gathers) ----

template <int FOUT>
__global__ __launch_bounds__(256) void edge_kernel(
    const ushort* __restrict__ xl, const ushort* __restrict__ xr,
    const int* __restrict__ csr_off, const int* __restrict__ csr_src,
    const float* __restrict__ a, const float* __restrict__ b,
    const float* __restrict__ gam, const float* __restrict__ bet,
    ushort* __restrict__ hout) {
  constexpr int GROUP = FOUT / 8;   // 16 / 8 / 4
  constexpr int GPB = 256 / GROUP;  // 16 / 32 / 64
  int gid = blockIdx.x * GPB + threadIdx.x / GROUP;
  int lane = threadIdx.x % GROUP;
  const uint4* xl4 = (const uint4*)xl;

  float xrf[8];
  cvt8(((const uint4*)xr)[gid * GROUP + lane], xrf);
  float av[8];
  {
    float4 a0 = ((const float4*)a)[lane * 2], a1 = ((const float4*)a)[lane * 2 + 1];
    av[0] = a0.x; av[1] = a0.y; av[2] = a0.z; av[3] = a0.w;
    av[4] = a1.x; av[5] = a1.y; av[6] = a1.z; av[7] = a1.w;
  }
  int beg = csr_off[gid], end = csr_off[gid + 1];

  float m = -INFINITY, den = 0.f;
  float acc[8] = {0.f, 0.f, 0.f, 0.f, 0.f, 0.f, 0.f, 0.f};
  int i = beg;
  for (; i + 2 <= end; i += 2) {
    int s0 = csr_src[i], s1 = csr_src[i + 1];
    uint4 v0 = xl4[(size_t)s0 * GROUP + lane];
    uint4 v1 = xl4[(size_t)s1 * GROUP + lane];
    float x0[8], x1[8];
    cvt8(v0, x0); cvt8(v1, x1);
    float sc0 = 0.f, sc1 = 0.f;
#pragma unroll
    for (int j = 0; j < 8; ++j) {
      float z0 = x0[j] + xrf[j];
      float z1 = x1[j] + xrf[j];
      sc0 = fmaf(fmaxf(z0, 0.2f * z0), av[j], sc0);
      sc1 = fmaf(fmaxf(z1, 0.2f * z1), av[j], sc1);
    }
#pragma unroll
    for (int wd = GROUP >> 1; wd >= 1; wd >>= 1) {
      sc0 += __shfl_xor(sc0, wd);
      sc1 += __shfl_xor(sc1, wd);
    }
    float m2 = fmaxf(m, fmaxf(sc0, sc1));
    float scale = __expf(m - m2);
    float p0 = __expf(sc0 - m2), p1 = __expf(sc1 - m2);
    den = den * scale + p0 + p1;
#pragma unroll
    for (int j = 0; j < 8; ++j) acc[j] = acc[j] * scale + p0 * x0[j] + p1 * x1[j];
    m = m2;
  }
  if (i < end) {
    int s0 = csr_src[i];
    uint4 v0 = xl4[(size_t)s0 * GROUP + lane];
    float x0[8];
    cvt8(v0, x0);
    float sc0 = 0.f;
#pragma unroll
    for (int j = 0; j < 8; ++j) {
      float z0 = x0[j] + xrf[j];
      sc0 = fmaf(fmaxf(z0, 0.2f * z0), av[j], sc0);
    }
#pragma unroll
    for (int wd = GROUP >> 1; wd >= 1; wd >>= 1) sc0 += __shfl_xor(sc0, wd);
    float m2 = fmaxf(m, sc0);
    float scale = __expf(m - m2);
    float p0 = __expf(sc0 - m2);
    den = den * scale + p0;
#pragma unroll
    for (int j = 0; j < 8; ++j) acc[j] = acc[j] * scale + p0 * x0[j];
    m = m2;
  }
  float inv = 1.f / den;
  float4 b0 = ((const float4*)b)[lane * 2], b1 = ((const float4*)b)[lane * 2 + 1];
  float4 g0 = ((const float4*)gam)[lane * 2], g1 = ((const float4*)gam)[lane * 2 + 1];
  float4 e0 = ((const float4*)bet)[lane * 2], e1 = ((const float4*)bet)[lane * 2 + 1];
  float bb[8] = {b0.x, b0.y, b0.z, b0.w, b1.x, b1.y, b1.z, b1.w};
  float gg[8] = {g0.x, g0.y, g0.z, g0.w, g1.x, g1.y, g1.z, g1.w};
  float ee[8] = {e0.x, e0.y, e0.z, e0.w, e1.x, e1.y, e1.z, e1.w};
  float o[8];
#pragma unroll
  for (int j = 0; j < 8; ++j)
    o[j] = fmaxf(acc[j] * inv + bb[j], 0.f) * (gg[j] * BNS) + ee[j];
  uint4 pv;
  pv.x = pack_bf2(o[0], o[1]); pv.y = pack_bf2(o[2], o[3]);
  pv.z = pack_bf2(o[4], o[5]); pv.w = pack_bf2(o[6], o[7]);
  ((uint4*)hout)[gid * GROUP + lane] = pv;
}

// ---------------- pooling (segment sum over sorted batch, bf16 input) --------

template <int FOUT>
__global__ __launch_bounds__(64) void pool_kernel(const ushort* __restrict__ h,
                                                  const int* __restrict__ goff,
                                                  float* __restrict__ pooled,
                                                  int colbase, int colbase2) {
  int g = blockIdx.x;
  int t = threadIdx.x;
  constexpr int PAIRS = FOUT / 2;
  if (t >= PAIRS) return;
  float a0 = 0.f, a1 = 0.f;
  int b0 = goff[g], b1 = goff[g + 1];
  const uint* h32 = (const uint*)h;
  for (int n = b0; n < b1; ++n) {
    uint v = h32[(size_t)n * PAIRS + t];
    a0 += lo_bf(v);
    a1 += hi_bf(v);
  }
  pooled[g * 256 + colbase + 2 * t] = a0;
  pooled[g * 256 + colbase + 2 * t + 1] = a1;
  if (colbase2 >= 0) {
    pooled[g * 256 + colbase2 + 2 * t] = a0;
    pooled[g * 256 + colbase2 + 2 * t + 1] = a1;
  }
}

// ---------------- MLP head + outputs ----------------

__global__ __launch_bounds__(128) void mlp_kernel(
    const float* __restrict__ pooled, const float* __restrict__ W1,
    const float* __restrict__ b1, const float* __restrict__ g5,
    const float* __restrict__ be5, const float* __restrict__ W2,
    const float* __restrict__ b2, float* __restrict__ out) {
  __shared__ float p[256];
  __shared__ float hid[128];
  __shared__ float lg[16];
  int g = blockIdx.x, t = threadIdx.x;
  p[t] = pooled[g * 256 + t];
  p[t + 128] = pooled[g * 256 + 128 + t];
  __syncthreads();
  float acc = b1[t];
  for (int k = 0; k < 256; ++k) acc = fmaf(p[k], W1[k * 128 + t], acc);
  acc = fmaxf(acc, 0.f) * (g5[t] * BNS) + be5[t];
  hid[t] = acc;
  __syncthreads();
  if (t < 16) {
    float l = b2[t];
    for (int k = 0; k < 128; ++k) l = fmaf(hid[k], W2[k * 16 + t], l);
    lg[t] = l;
  }
  __syncthreads();
  if (t < 16) {
    float l = lg[t];
    float m = lg[0];
    for (int k = 1; k < 16; ++k) m = fmaxf(m, lg[k]);
    float se = 0.f;
    for (int k = 0; k < 16; ++k) se += __expf(lg[k] - m);
    out[g * 16 + t] = 1.f / (1.f + __expf(-l));       // sigmoid
    out[NG * 16 + g * 16 + t] = l - m - __logf(se);   // log_softmax
  }
}

// ---------------- launch ----------------

extern "C" void kernel_launch(void* const* d_in, const int* in_sizes, int n_in,
                              void* d_out, int out_size, void* d_ws, size_t ws_size,
                              hipStream_t stream) {
  const float* x = (const float*)d_in[0];
  const int* ei = (const int*)d_in[1];
  const int* batch = (const int*)d_in[2];
  const float* Wl1 = (const float*)d_in[4];
  const float* Wr1 = (const float*)d_in[5];
  const float* a1 = (const float*)d_in[6];
  const float* b1 = (const float*)d_in[7];
  const float* g1 = (const float*)d_in[8];
  const float* be1 = (const float*)d_in[9];
  const float* Wl2 = (const float*)d_in[10];
  const float* Wr2 = (const float*)d_in[11];
  const float* a2 = (const float*)d_in[12];
  const float* b2 = (const float*)d_in[13];
  const float* g2 = (const float*)d_in[14];
  const float* be2 = (const float*)d_in[15];
  const float* Wl3 = (const float*)d_in[16];
  const float* Wr3 = (const float*)d_in[17];
  const float* a3 = (const float*)d_in[18];
  const float* b3 = (const float*)d_in[19];
  const float* g3 = (const float*)d_in[20];
  const float* be3 = (const float*)d_in[21];
  // layer 4 (d_in[22..27]) is dead in the reference (h4 = h3) — skipped.
  const float* lin1_W = (const float*)d_in[28];
  const float* lin1_b = (const float*)d_in[29];
  const float* g5 = (const float*)d_in[30];
  const float* be5 = (const float*)d_in[31];
  const float* lin2_W = (const float*)d_in[32];
  const float* lin2_b = (const float*)d_in[33];
  float* out = (float*)d_out;

  // workspace carve (16B-aligned chunks)
  char* w = (char*)d_ws;
  ushort* xb = (ushort*)w;  w += (size_t)NN * 128 * 2;  // 16 MB
  ushort* xl = (ushort*)w;  w += (size_t)NN * 128 * 2;  // 16 MB
  ushort* xr = (ushort*)w;  w += (size_t)NN * 128 * 2;  // 16 MB
  ushort* h  = (ushort*)w;  w += (size_t)NN * 128 * 2;  // 16 MB
  ushort* P1l = (ushort*)w; w += 65536;
  ushort* P1r = (ushort*)w; w += 65536;
  ushort* P2l = (ushort*)w; w += 65536;
  ushort* P2r = (ushort*)w; w += 65536;
  ushort* P3l = (ushort*)w; w += 65536;
  ushort* P3r = (ushort*)w; w += 65536;
  int* counts = (int*)w;    w += (size_t)NN * 4;
  int* csr_off = (int*)w;   w += (size_t)(NN + 4) * 4;
  int* csr_src = (int*)w;   w += (size_t)ET * 4;
  int* gcnt = (int*)w;      w += (size_t)NG * 4;
  int* goff = (int*)w;      w += (size_t)(NG + 4) * 4;
  float* pooled = (float*)w; w += (size_t)NG * 256 * 4;

  hipMemsetAsync(counts, 0, (size_t)NN * 4, stream);
  hipMemsetAsync(gcnt, 0, (size_t)NG * 4, stream);

  cvt_kernel<<<NN * 128 / 4 / 256, 256, 0, stream>>>(x, xb);
  pack_kernel<<<26, 256, 0, stream>>>(Wl1, Wr1, Wl2, Wr2, Wl3, Wr3,
                                      P1l, P1r, P2l, P2r, P3l, P3r);
  hist_kernel<<<(ET + 255) / 256, 256, 0, stream>>>(ei, counts);
  scan_kernel<<<1, 1024, 0, stream>>>(counts, csr_off, NN, 1);
  scatter_kernel<<<(ET + 255) / 256, 256, 0, stream>>>(ei, counts, csr_src);
  ghist_kernel<<<NN / 256, 256, 0, stream>>>(batch, gcnt);
  scan_kernel<<<1, 1024, 0, stream>>>(gcnt, goff, NG, 0);

  // ---- layer 1: 128 -> 128
  gemm_mfma<128, 128, 8><<<512, 256, 0, stream>>>(xb, P1l, P1r, xl, xr);
  edge_kernel<128><<<NN / 16, 256, 0, stream>>>(xl, xr, csr_off, csr_src,
                                                a1, b1, g1, be1, h);
  pool_kernel<128><<<NG, 64, 0, stream>>>(h, goff, pooled, 0, -1);

  // ---- layer 2: 128 -> 64
  gemm_mfma<128, 64, 8><<<512, 256, 0, stream>>>(h, P2l, P2r, xl, xr);
  edge_kernel<64><<<NN / 32, 256, 0, stream>>>(xl, xr, csr_off, csr_src,
                                               a2, b2, g2, be2, h);
  pool_kernel<64><<<NG, 64, 0, stream>>>(h, goff, pooled, 128, -1);

  // ---- layer 3: 64 -> 32
  gemm_mfma<64, 32, 8><<<256, 256, 0, stream>>>(h, P3l, P3r, xl, xr);
  edge_kernel<32><<<NN / 64, 256, 0, stream>>>(xl, xr, csr_off, csr_src,
                                               a3, b3, g3, be3, h);
  pool_kernel<32><<<NG, 64, 0, stream>>>(h, goff, pooled, 192, 224);

  // ---- MLP head
  mlp_kernel<<<NG, 128, 0, stream>>>(pooled, lin1_W, lin1_b, g5, be5, lin2_W,
                                     lin2_b, out);
}

// Round 3
// 417.189 us; speedup vs baseline: 2.2841x; 1.4015x over previous
//
#include <hip/hip_runtime.h>
#include <hip/hip_bf16.h>
#include <math.h>

#define NN 65536
#define EE 1048576
#define ET (EE + NN)      // 1114112 edges incl. self loops
#define NG 512

typedef __attribute__((ext_vector_type(8))) short bf16x8;
typedef __attribute__((ext_vector_type(4))) float f32x4;

__device__ __constant__ const float BNS = 0.9999950000374997f; // 1/sqrt(1+1e-5)

// ---------------- bf16 helpers ----------------
__device__ inline float lo_bf(uint u) { union { uint i; float f; } v; v.i = u << 16; return v.f; }
__device__ inline float hi_bf(uint u) { union { uint i; float f; } v; v.i = u & 0xFFFF0000u; return v.f; }
__device__ inline uint f2bf(float f) {
  union { float f; uint i; } v; v.f = f;
  uint r = v.i + 0x7FFFu + ((v.i >> 16) & 1u);  // RTNE
  return r >> 16;
}
__device__ inline uint pack_bf2(float a, float b) { return f2bf(a) | (f2bf(b) << 16); }
__device__ inline void cvt8(uint4 v, float* o) {
  o[0] = lo_bf(v.x); o[1] = hi_bf(v.x); o[2] = lo_bf(v.y); o[3] = hi_bf(v.y);
  o[4] = lo_bf(v.z); o[5] = hi_bf(v.z); o[6] = lo_bf(v.w); o[7] = hi_bf(v.w);
}

// ---------------- CSR build ----------------

__global__ __launch_bounds__(256) void hist_kernel(const int* __restrict__ ei,
                                                   int* __restrict__ counts) {
  int i = blockIdx.x * 256 + threadIdx.x;
  if (i < ET) {
    int d = (i < EE) ? ei[EE + i] : (i - EE);
    atomicAdd(&counts[d], 1);
  }
}

// multi-block scan over NN=65536 = 64 blocks x 1024 elems (int4 per thread)
__global__ __launch_bounds__(256) void scan1_kernel(const int* __restrict__ counts,
                                                    int* __restrict__ bsum) {
  __shared__ int ws[4];
  int b = blockIdx.x, t = threadIdx.x;
  int4 v = ((const int4*)(counts + b * 1024))[t];
  int s = v.x + v.y + v.z + v.w;
#pragma unroll
  for (int d = 1; d < 64; d <<= 1) s += __shfl_xor(s, d);
  if ((t & 63) == 0) ws[t >> 6] = s;
  __syncthreads();
  if (t == 0) bsum[b] = ws[0] + ws[1] + ws[2] + ws[3];
}

__global__ __launch_bounds__(64) void scan2_kernel(const int* __restrict__ bsum,
                                                   int* __restrict__ boff,
                                                   int* __restrict__ off_last) {
  int t = threadIdx.x;
  int v = bsum[t];
  int s = v;
#pragma unroll
  for (int d = 1; d < 64; d <<= 1) {
    int u = __shfl_up(s, d);
    if (t >= d) s += u;
  }
  boff[t] = s - v;             // exclusive block offset
  if (t == 63) *off_last = s;  // grand total -> off[NN]
}

// reads counts, writes csr_off AND rewrites counts in-place as scatter cursor
__global__ __launch_bounds__(256) void scan3_kernel(int* __restrict__ counts,
                                                    const int* __restrict__ boff,
                                                    int* __restrict__ off) {
  __shared__ int wsum[4];
  int b = blockIdx.x, t = threadIdx.x;
  int base = b * 1024;
  int4 v = ((const int4*)(counts + base))[t];
  int s = v.x + v.y + v.z + v.w;
  int inc = s;
#pragma unroll
  for (int d = 1; d < 64; d <<= 1) {
    int u = __shfl_up(inc, d);
    if ((t & 63) >= d) inc += u;
  }
  int wave = t >> 6;
  if ((t & 63) == 63) wsum[wave] = inc;
  __syncthreads();
  int wadd = 0;
  for (int wv = 0; wv < wave; ++wv) wadd += wsum[wv];
  int ex = inc - s + wadd + boff[b];
  int4 o;
  o.x = ex; o.y = ex + v.x; o.z = o.y + v.y; o.w = o.z + v.z;
  ((int4*)(off + base))[t] = o;
  ((int4*)(counts + base))[t] = o;   // cursor copy, in place
}

__global__ __launch_bounds__(256) void scatter_kernel(const int* __restrict__ ei,
                                                      int* __restrict__ cursor,
                                                      int* __restrict__ csr_src) {
  int i = blockIdx.x * 256 + threadIdx.x;
  if (i < ET) {
    int d, s;
    if (i < EE) { d = ei[EE + i]; s = ei[i]; }
    else        { d = i - EE;     s = d;     }
    int pos = atomicAdd(&cursor[d], 1);
    csr_src[pos] = s;
  }
}

// batch is sorted: graph boundaries by binary search
__global__ __launch_bounds__(256) void gbound_kernel(const int* __restrict__ batch,
                                                     int* __restrict__ goff) {
  int g = blockIdx.x * 256 + threadIdx.x;
  if (g > NG) return;
  int lo = 0, hi = NN;
  while (lo < hi) {
    int mid = (lo + hi) >> 1;
    if (batch[mid] < g) lo = mid + 1; else hi = mid;
  }
  goff[g] = lo;   // first index with batch[i] >= g
}

// ---------------- input convert & weight pack ----------------

__global__ __launch_bounds__(256) void cvt_kernel(const float* __restrict__ x,
                                                  ushort* __restrict__ xb) {
  int i = blockIdx.x * 256 + threadIdx.x;   // 4 floats per thread
  float4 v = ((const float4*)x)[i];
  uint2 o; o.x = pack_bf2(v.x, v.y); o.y = pack_bf2(v.z, v.w);
  ((uint2*)xb)[i] = o;
}

// pack W [FIN x FOUT] f32 into MFMA A-fragment layout (W^T tiles), bf16
__global__ __launch_bounds__(256) void pack_kernel(
    const float* __restrict__ Wl1, const float* __restrict__ Wr1,
    const float* __restrict__ Wl2, const float* __restrict__ Wr2,
    const float* __restrict__ Wl3, const float* __restrict__ Wr3,
    ushort* __restrict__ P1l, ushort* __restrict__ P1r,
    ushort* __restrict__ P2l, ushort* __restrict__ P2r,
    ushort* __restrict__ P3l, ushort* __restrict__ P3r) {
  int b = blockIdx.x;
  const float* W; ushort* P; int FIN, FOUT, base;
  if (b < 8)       { W = Wl1; P = P1l; FIN = 128; FOUT = 128; base = b; }
  else if (b < 16) { W = Wr1; P = P1r; FIN = 128; FOUT = 128; base = b - 8; }
  else if (b < 20) { W = Wl2; P = P2l; FIN = 128; FOUT = 64;  base = b - 16; }
  else if (b < 24) { W = Wr2; P = P2r; FIN = 128; FOUT = 64;  base = b - 20; }
  else if (b < 25) { W = Wl3; P = P3l; FIN = 64;  FOUT = 32;  base = 0; }
  else             { W = Wr3; P = P3r; FIN = 64;  FOUT = 32;  base = 0; }
  int tid = base * 256 + threadIdx.x;
  int KS = FIN / 32, NF = FOUT / 16;
  if (tid >= NF * KS * 64) return;
  int lane = tid & 63, t = (tid >> 6) % KS, cf = (tid >> 6) / KS;
  int f = cf * 16 + (lane & 15);
  int k0 = t * 32 + (lane >> 4) * 8;
  uint4 v;
  v.x = pack_bf2(W[(k0 + 0) * FOUT + f], W[(k0 + 1) * FOUT + f]);
  v.y = pack_bf2(W[(k0 + 2) * FOUT + f], W[(k0 + 3) * FOUT + f]);
  v.z = pack_bf2(W[(k0 + 4) * FOUT + f], W[(k0 + 5) * FOUT + f]);
  v.w = pack_bf2(W[(k0 + 6) * FOUT + f], W[(k0 + 7) * FOUT + f]);
  ((uint4*)P)[tid] = v;
}

// ---------------- MFMA GEMM: xl = xin@Wl, xr = xin@Wr (all bf16) --------------

template <int FIN, int FOUT, int TILES>
__global__ __launch_bounds__(256) void gemm_mfma(
    const ushort* __restrict__ xin, const ushort* __restrict__ Wlp,
    const ushort* __restrict__ Wrp, ushort* __restrict__ xl,
    ushort* __restrict__ xr) {
  constexpr int KS = FIN / 32;
  constexpr int NF = FOUT / 16;
  constexpr int FW = (NF < 4) ? NF : 4;   // waves covering F
  constexpr int CFW = NF / FW;            // F-frags per wave
  constexpr int NW = 4 / FW;              // node groups per block
  const int w = threadIdx.x >> 6, lane = threadIdx.x & 63;
  const int fseg = w % FW, ng = w / FW;
  const int l15 = lane & 15, lhi = lane >> 4;

  bf16x8 wfl[CFW][KS], wfr[CFW][KS];
#pragma unroll
  for (int c = 0; c < CFW; ++c)
#pragma unroll
    for (int t = 0; t < KS; ++t) {
      int idx = ((fseg * CFW + c) * KS + t) * 64 + lane;
      wfl[c][t] = ((const bf16x8*)Wlp)[idx];
      wfr[c][t] = ((const bf16x8*)Wrp)[idx];
    }

  size_t tile0 = ((size_t)blockIdx.x * NW + ng) * TILES;
  for (int it = 0; it < TILES; ++it) {
    int mb = (int)(tile0 + it) * 16;
    const bf16x8* xrow = (const bf16x8*)(xin + (size_t)(mb + l15) * FIN);
    bf16x8 bx[KS];
#pragma unroll
    for (int t = 0; t < KS; ++t) bx[t] = xrow[t * 4 + lhi];  // k = t*32 + lhi*8
    f32x4 accl[CFW], accr[CFW];
#pragma unroll
    for (int c = 0; c < CFW; ++c) {
      accl[c] = (f32x4){0.f, 0.f, 0.f, 0.f};
      accr[c] = (f32x4){0.f, 0.f, 0.f, 0.f};
    }
#pragma unroll
    for (int t = 0; t < KS; ++t)
#pragma unroll
      for (int c = 0; c < CFW; ++c) {
        accl[c] = __builtin_amdgcn_mfma_f32_16x16x32_bf16(wfl[c][t], bx[t], accl[c], 0, 0, 0);
        accr[c] = __builtin_amdgcn_mfma_f32_16x16x32_bf16(wfr[c][t], bx[t], accr[c], 0, 0, 0);
      }
#pragma unroll
    for (int c = 0; c < CFW; ++c) {
      int f0 = (fseg * CFW + c) * 16 + lhi * 4;
      size_t o = (size_t)(mb + l15) * FOUT + f0;
      uint2 vl; vl.x = pack_bf2(accl[c][0], accl[c][1]); vl.y = pack_bf2(accl[c][2], accl[c][3]);
      *(uint2*)(xl + o) = vl;
      uint2 vr; vr.x = pack_bf2(accr[c][0], accr[c][1]); vr.y = pack_bf2(accr[c][2], accr[c][3]);
      *(uint2*)(xr + o) = vr;
    }
  }
}

// ---------------- edge aggregation (online segment softmax, bf16 gathers) ----

template <int FOUT>
__global__ __launch_bounds__(256) void edge_kernel(
    const ushort* __restrict__ xl, const ushort* __restrict__ xr,
    const int* __restrict__ csr_off, const int* __restrict__ csr_src,
    const float* __restrict__ a, const float* __restrict__ b,
    const float* __restrict__ gam, const float* __restrict__ bet,
    ushort* __restrict__ hout) {
  constexpr int GROUP = FOUT / 8;   // 16 / 8 / 4
  constexpr int GPB = 256 / GROUP;
  int gid = blockIdx.x * GPB + threadIdx.x / GROUP;
  int lane = threadIdx.x % GROUP;
  const uint4* xl4 = (const uint4*)xl;

  float xrf[8];
  cvt8(((const uint4*)xr)[gid * GROUP + lane], xrf);
  float av[8];
  {
    float4 a0 = ((const float4*)a)[lane * 2], a1 = ((const float4*)a)[lane * 2 + 1];
    av[0] = a0.x; av[1] = a0.y; av[2] = a0.z; av[3] = a0.w;
    av[4] = a1.x; av[5] = a1.y; av[6] = a1.z; av[7] = a1.w;
  }
  int beg = csr_off[gid], end = csr_off[gid + 1];

  float m = -INFINITY, den = 0.f;
  float acc[8] = {0.f, 0.f, 0.f, 0.f, 0.f, 0.f, 0.f, 0.f};
  int i = beg;
  for (; i + 2 <= end; i += 2) {
    int s0 = csr_src[i], s1 = csr_src[i + 1];
    uint4 v0 = xl4[(size_t)s0 * GROUP + lane];
    uint4 v1 = xl4[(size_t)s1 * GROUP + lane];
    float x0[8], x1[8];
    cvt8(v0, x0); cvt8(v1, x1);
    float sc0 = 0.f, sc1 = 0.f;
#pragma unroll
    for (int j = 0; j < 8; ++j) {
      float z0 = x0[j] + xrf[j];
      float z1 = x1[j] + xrf[j];
      sc0 = fmaf(fmaxf(z0, 0.2f * z0), av[j], sc0);
      sc1 = fmaf(fmaxf(z1, 0.2f * z1), av[j], sc1);
    }
#pragma unroll
    for (int wd = GROUP >> 1; wd >= 1; wd >>= 1) {
      sc0 += __shfl_xor(sc0, wd);
      sc1 += __shfl_xor(sc1, wd);
    }
    float m2 = fmaxf(m, fmaxf(sc0, sc1));
    float scale = __expf(m - m2);
    float p0 = __expf(sc0 - m2), p1 = __expf(sc1 - m2);
    den = den * scale + p0 + p1;
#pragma unroll
    for (int j = 0; j < 8; ++j) acc[j] = acc[j] * scale + p0 * x0[j] + p1 * x1[j];
    m = m2;
  }
  if (i < end) {
    int s0 = csr_src[i];
    uint4 v0 = xl4[(size_t)s0 * GROUP + lane];
    float x0[8];
    cvt8(v0, x0);
    float sc0 = 0.f;
#pragma unroll
    for (int j = 0; j < 8; ++j) {
      float z0 = x0[j] + xrf[j];
      sc0 = fmaf(fmaxf(z0, 0.2f * z0), av[j], sc0);
    }
#pragma unroll
    for (int wd = GROUP >> 1; wd >= 1; wd >>= 1) sc0 += __shfl_xor(sc0, wd);
    float m2 = fmaxf(m, sc0);
    float scale = __expf(m - m2);
    float p0 = __expf(sc0 - m2);
    den = den * scale + p0;
#pragma unroll
    for (int j = 0; j < 8; ++j) acc[j] = acc[j] * scale + p0 * x0[j];
    m = m2;
  }
  float inv = 1.f / den;
  float4 b0 = ((const float4*)b)[lane * 2], b1 = ((const float4*)b)[lane * 2 + 1];
  float4 g0 = ((const float4*)gam)[lane * 2], g1 = ((const float4*)gam)[lane * 2 + 1];
  float4 e0 = ((const float4*)bet)[lane * 2], e1 = ((const float4*)bet)[lane * 2 + 1];
  float bb[8] = {b0.x, b0.y, b0.z, b0.w, b1.x, b1.y, b1.z, b1.w};
  float gg[8] = {g0.x, g0.y, g0.z, g0.w, g1.x, g1.y, g1.z, g1.w};
  float ee[8] = {e0.x, e0.y, e0.z, e0.w, e1.x, e1.y, e1.z, e1.w};
  float o[8];
#pragma unroll
  for (int j = 0; j < 8; ++j)
    o[j] = fmaxf(acc[j] * inv + bb[j], 0.f) * (gg[j] * BNS) + ee[j];
  uint4 pv;
  pv.x = pack_bf2(o[0], o[1]); pv.y = pack_bf2(o[2], o[3]);
  pv.z = pack_bf2(o[4], o[5]); pv.w = pack_bf2(o[6], o[7]);
  ((uint4*)hout)[gid * GROUP + lane] = pv;
}

// ---------------- pooling (segment sum over sorted batch, bf16 input) --------

template <int FOUT>
__global__ __launch_bounds__(64) void pool_kernel(const ushort* __restrict__ h,
                                                  const int* __restrict__ goff,
                                                  float* __restrict__ pooled,
                                                  int colbase, int colbase2) {
  int g = blockIdx.x;
  int t = threadIdx.x;
  constexpr int PAIRS = FOUT / 2;
  if (t >= PAIRS) return;
  float a0 = 0.f, a1 = 0.f;
  int b0 = goff[g], b1 = goff[g + 1];
  const uint* h32 = (const uint*)h;
  for (int n = b0; n < b1; ++n) {
    uint v = h32[(size_t)n * PAIRS + t];
    a0 += lo_bf(v);
    a1 += hi_bf(v);
  }
  pooled[g * 256 + colbase + 2 * t] = a0;
  pooled[g * 256 + colbase + 2 * t + 1] = a1;
  if (colbase2 >= 0) {
    pooled[g * 256 + colbase2 + 2 * t] = a0;
    pooled[g * 256 + colbase2 + 2 * t + 1] = a1;
  }
}

// ---------------- MLP head + outputs ----------------

__global__ __launch_bounds__(128) void mlp_kernel(
    const float* __restrict__ pooled, const float* __restrict__ W1,
    const float* __restrict__ b1, const float* __restrict__ g5,
    const float* __restrict__ be5, const float* __restrict__ W2,
    const float* __restrict__ b2, float* __restrict__ out) {
  __shared__ float p[256];
  __shared__ float hid[128];
  __shared__ float lg[16];
  int g = blockIdx.x, t = threadIdx.x;
  p[t] = pooled[g * 256 + t];
  p[t + 128] = pooled[g * 256 + 128 + t];
  __syncthreads();
  float acc = b1[t];
  for (int k = 0; k < 256; ++k) acc = fmaf(p[k], W1[k * 128 + t], acc);
  acc = fmaxf(acc, 0.f) * (g5[t] * BNS) + be5[t];
  hid[t] = acc;
  __syncthreads();
  if (t < 16) {
    float l = b2[t];
    for (int k = 0; k < 128; ++k) l = fmaf(hid[k], W2[k * 16 + t], l);
    lg[t] = l;
  }
  __syncthreads();
  if (t < 16) {
    float l = lg[t];
    float m = lg[0];
    for (int k = 1; k < 16; ++k) m = fmaxf(m, lg[k]);
    float se = 0.f;
    for (int k = 0; k < 16; ++k) se += __expf(lg[k] - m);
    out[g * 16 + t] = 1.f / (1.f + __expf(-l));       // sigmoid
    out[NG * 16 + g * 16 + t] = l - m - __logf(se);   // log_softmax
  }
}

// ---------------- launch ----------------

extern "C" void kernel_launch(void* const* d_in, const int* in_sizes, int n_in,
                              void* d_out, int out_size, void* d_ws, size_t ws_size,
                              hipStream_t stream) {
  const float* x = (const float*)d_in[0];
  const int* ei = (const int*)d_in[1];
  const int* batch = (const int*)d_in[2];
  const float* Wl1 = (const float*)d_in[4];
  const float* Wr1 = (const float*)d_in[5];
  const float* a1 = (const float*)d_in[6];
  const float* b1 = (const float*)d_in[7];
  const float* g1 = (const float*)d_in[8];
  const float* be1 = (const float*)d_in[9];
  const float* Wl2 = (const float*)d_in[10];
  const float* Wr2 = (const float*)d_in[11];
  const float* a2 = (const float*)d_in[12];
  const float* b2 = (const float*)d_in[13];
  const float* g2 = (const float*)d_in[14];
  const float* be2 = (const float*)d_in[15];
  const float* Wl3 = (const float*)d_in[16];
  const float* Wr3 = (const float*)d_in[17];
  const float* a3 = (const float*)d_in[18];
  const float* b3 = (const float*)d_in[19];
  const float* g3 = (const float*)d_in[20];
  const float* be3 = (const float*)d_in[21];
  // layer 4 (d_in[22..27]) is dead in the reference (h4 = h3) — skipped.
  const float* lin1_W = (const float*)d_in[28];
  const float* lin1_b = (const float*)d_in[29];
  const float* g5 = (const float*)d_in[30];
  const float* be5 = (const float*)d_in[31];
  const float* lin2_W = (const float*)d_in[32];
  const float* lin2_b = (const float*)d_in[33];
  float* out = (float*)d_out;

  // workspace carve (16B-aligned chunks)
  char* w = (char*)d_ws;
  ushort* xb = (ushort*)w;  w += (size_t)NN * 128 * 2;  // 16 MB
  ushort* xl = (ushort*)w;  w += (size_t)NN * 128 * 2;  // 16 MB
  ushort* xr = (ushort*)w;  w += (size_t)NN * 128 * 2;  // 16 MB
  ushort* h  = (ushort*)w;  w += (size_t)NN * 128 * 2;  // 16 MB
  ushort* P1l = (ushort*)w; w += 65536;
  ushort* P1r = (ushort*)w; w += 65536;
  ushort* P2l = (ushort*)w; w += 65536;
  ushort* P2r = (ushort*)w; w += 65536;
  ushort* P3l = (ushort*)w; w += 65536;
  ushort* P3r = (ushort*)w; w += 65536;
  int* counts = (int*)w;    w += (size_t)NN * 4;        // becomes scatter cursor
  int* csr_off = (int*)w;   w += (size_t)(NN + 4) * 4;
  int* csr_src = (int*)w;   w += (size_t)ET * 4;
  int* bsum = (int*)w;      w += 64 * 4;
  int* boff = (int*)w;      w += 64 * 4;
  int* goff = (int*)w;      w += (size_t)(NG + 4) * 4;
  float* pooled = (float*)w; w += (size_t)NG * 256 * 4;

  hipMemsetAsync(counts, 0, (size_t)NN * 4, stream);

  cvt_kernel<<<NN * 128 / 4 / 256, 256, 0, stream>>>(x, xb);
  pack_kernel<<<26, 256, 0, stream>>>(Wl1, Wr1, Wl2, Wr2, Wl3, Wr3,
                                      P1l, P1r, P2l, P2r, P3l, P3r);
  hist_kernel<<<(ET + 255) / 256, 256, 0, stream>>>(ei, counts);
  scan1_kernel<<<64, 256, 0, stream>>>(counts, bsum);
  scan2_kernel<<<1, 64, 0, stream>>>(bsum, boff, &csr_off[NN]);
  scan3_kernel<<<64, 256, 0, stream>>>(counts, boff, csr_off);
  scatter_kernel<<<(ET + 255) / 256, 256, 0, stream>>>(ei, counts, csr_src);
  gbound_kernel<<<3, 256, 0, stream>>>(batch, goff);

  // ---- layer 1: 128 -> 128
  gemm_mfma<128, 128, 8><<<512, 256, 0, stream>>>(xb, P1l, P1r, xl, xr);
  edge_kernel<128><<<NN / 16, 256, 0, stream>>>(xl, xr, csr_off, csr_src,
                                                a1, b1, g1, be1, h);
  pool_kernel<128><<<NG, 64, 0, stream>>>(h, goff, pooled, 0, -1);

  // ---- layer 2: 128 -> 64
  gemm_mfma<128, 64, 8><<<512, 256, 0, stream>>>(h, P2l, P2r, xl, xr);
  edge_kernel<64><<<NN / 32, 256, 0, stream>>>(xl, xr, csr_off, csr_src,
                                               a2, b2, g2, be2, h);
  pool_kernel<64><<<NG, 64, 0, stream>>>(h, goff, pooled, 128, -1);

  // ---- layer 3: 64 -> 32
  gemm_mfma<64, 32, 8><<<256, 256, 0, stream>>>(h, P3l, P3r, xl, xr);
  edge_kernel<32><<<NN / 64, 256, 0, stream>>>(xl, xr, csr_off, csr_src,
                                               a3, b3, g3, be3, h);
  pool_kernel<32><<<NG, 64, 0, stream>>>(h, goff, pooled, 192, 224);

  // ---- MLP head
  mlp_kernel<<<NG, 128, 0, stream>>>(pooled, lin1_W, lin1_b, g5, be5, lin2_W,
                                     lin2_b, out);
}

// Round 4
// 377.482 us; speedup vs baseline: 2.5243x; 1.1052x over previous
//
#include <hip/hip_runtime.h>
#include <hip/hip_bf16.h>
#include <math.h>

#define NN 65536
#define EE 1048576
#define ET (EE + NN)      // 1114112 edges incl. self loops
#define NG 512

// fused-kernel block splits
#define HIST_B 1088       // ET/4/256 exactly
#define CVT_B  512
#define PACK_B 26
#define GB_B   3
#define PRE_B  (HIST_B + CVT_B + PACK_B + GB_B)
#define SCAT_B 1088       // ET/4/256 exactly
#define GEMM1_B 512
#define SG1_B  (SCAT_B + GEMM1_B)
#define POOL_B 512

typedef __attribute__((ext_vector_type(8))) short bf16x8;
typedef __attribute__((ext_vector_type(4))) float f32x4;

__device__ __constant__ const float BNS = 0.9999950000374997f; // 1/sqrt(1+1e-5)

// ---------------- bf16 helpers ----------------
__device__ inline float lo_bf(uint u) { union { uint i; float f; } v; v.i = u << 16; return v.f; }
__device__ inline float hi_bf(uint u) { union { uint i; float f; } v; v.i = u & 0xFFFF0000u; return v.f; }
__device__ inline uint f2bf(float f) {
  union { float f; uint i; } v; v.f = f;
  uint r = v.i + 0x7FFFu + ((v.i >> 16) & 1u);  // RTNE
  return r >> 16;
}
__device__ inline uint pack_bf2(float a, float b) { return f2bf(a) | (f2bf(b) << 16); }
__device__ inline void cvt8(uint4 v, float* o) {
  o[0] = lo_bf(v.x); o[1] = hi_bf(v.x); o[2] = lo_bf(v.y); o[3] = hi_bf(v.y);
  o[4] = lo_bf(v.z); o[5] = hi_bf(v.z); o[6] = lo_bf(v.w); o[7] = hi_bf(v.w);
}

// ================= device bodies for fused kernels =================

__device__ void dev_hist(int lb, const int* __restrict__ ei,
                         int* __restrict__ counts) {
  int tid = lb * 256 + threadIdx.x;
  int i0 = tid * 4;
  if (i0 + 3 < EE) {
    int4 d4 = *(const int4*)(ei + EE + i0);
    atomicAdd(&counts[d4.x], 1);
    atomicAdd(&counts[d4.y], 1);
    atomicAdd(&counts[d4.z], 1);
    atomicAdd(&counts[d4.w], 1);
  } else {
#pragma unroll
    for (int k = 0; k < 4; ++k) {
      int i = i0 + k;
      if (i < ET) {
        int d = (i < EE) ? ei[EE + i] : (i - EE);
        atomicAdd(&counts[d], 1);
      }
    }
  }
}

__device__ void dev_cvt(int lb, const float* __restrict__ x,
                        ushort* __restrict__ xb) {
  for (int i = lb * 256 + threadIdx.x; i < NN * 32; i += CVT_B * 256) {
    float4 v = ((const float4*)x)[i];
    uint2 o; o.x = pack_bf2(v.x, v.y); o.y = pack_bf2(v.z, v.w);
    ((uint2*)xb)[i] = o;
  }
}

__device__ void dev_pack(int b,
    const float* __restrict__ Wl1, const float* __restrict__ Wr1,
    const float* __restrict__ Wl2, const float* __restrict__ Wr2,
    const float* __restrict__ Wl3, const float* __restrict__ Wr3,
    ushort* __restrict__ P1l, ushort* __restrict__ P1r,
    ushort* __restrict__ P2l, ushort* __restrict__ P2r,
    ushort* __restrict__ P3l, ushort* __restrict__ P3r) {
  const float* W; ushort* P; int FIN, FOUT, base;
  if (b < 8)       { W = Wl1; P = P1l; FIN = 128; FOUT = 128; base = b; }
  else if (b < 16) { W = Wr1; P = P1r; FIN = 128; FOUT = 128; base = b - 8; }
  else if (b < 20) { W = Wl2; P = P2l; FIN = 128; FOUT = 64;  base = b - 16; }
  else if (b < 24) { W = Wr2; P = P2r; FIN = 128; FOUT = 64;  base = b - 20; }
  else if (b < 25) { W = Wl3; P = P3l; FIN = 64;  FOUT = 32;  base = 0; }
  else             { W = Wr3; P = P3r; FIN = 64;  FOUT = 32;  base = 0; }
  int tid = base * 256 + threadIdx.x;
  int KS = FIN / 32, NF = FOUT / 16;
  if (tid >= NF * KS * 64) return;
  int lane = tid & 63, t = (tid >> 6) % KS, cf = (tid >> 6) / KS;
  int f = cf * 16 + (lane & 15);
  int k0 = t * 32 + (lane >> 4) * 8;
  uint4 v;
  v.x = pack_bf2(W[(k0 + 0) * FOUT + f], W[(k0 + 1) * FOUT + f]);
  v.y = pack_bf2(W[(k0 + 2) * FOUT + f], W[(k0 + 3) * FOUT + f]);
  v.z = pack_bf2(W[(k0 + 4) * FOUT + f], W[(k0 + 5) * FOUT + f]);
  v.w = pack_bf2(W[(k0 + 6) * FOUT + f], W[(k0 + 7) * FOUT + f]);
  ((uint4*)P)[tid] = v;
}

__device__ void dev_gbound(int lb, const int* __restrict__ batch,
                           int* __restrict__ goff) {
  int g = lb * 256 + threadIdx.x;
  if (g > NG) return;
  int lo = 0, hi = NN;
  while (lo < hi) {
    int mid = (lo + hi) >> 1;
    if (batch[mid] < g) lo = mid + 1; else hi = mid;
  }
  goff[g] = lo;
}

__device__ void dev_scatter(int lb, const int* __restrict__ ei,
                            int* __restrict__ cursor,
                            ushort* __restrict__ csr_src) {
  int tid = lb * 256 + threadIdx.x;
  int i0 = tid * 4;
  if (i0 + 3 < EE) {
    int4 s4 = *(const int4*)(ei + i0);
    int4 d4 = *(const int4*)(ei + EE + i0);
    int p0 = atomicAdd(&cursor[d4.x], 1);
    int p1 = atomicAdd(&cursor[d4.y], 1);
    int p2 = atomicAdd(&cursor[d4.z], 1);
    int p3 = atomicAdd(&cursor[d4.w], 1);
    csr_src[p0] = (ushort)s4.x;
    csr_src[p1] = (ushort)s4.y;
    csr_src[p2] = (ushort)s4.z;
    csr_src[p3] = (ushort)s4.w;
  } else {
#pragma unroll
    for (int k = 0; k < 4; ++k) {
      int i = i0 + k;
      if (i < ET) {
        int d, s;
        if (i < EE) { d = ei[EE + i]; s = ei[i]; }
        else        { d = i - EE;     s = d;     }
        int pos = atomicAdd(&cursor[d], 1);
        csr_src[pos] = (ushort)s;
      }
    }
  }
}

template <int FIN, int FOUT, int TILES>
__device__ void dev_gemm(int lb, const ushort* __restrict__ xin,
                         const ushort* __restrict__ Wlp,
                         const ushort* __restrict__ Wrp,
                         ushort* __restrict__ xl, ushort* __restrict__ xr) {
  constexpr int KS = FIN / 32;
  constexpr int NF = FOUT / 16;
  constexpr int FW = (NF < 4) ? NF : 4;
  constexpr int CFW = NF / FW;
  constexpr int NW = 4 / FW;
  const int w = threadIdx.x >> 6, lane = threadIdx.x & 63;
  const int fseg = w % FW, ng = w / FW;
  const int l15 = lane & 15, lhi = lane >> 4;

  bf16x8 wfl[CFW][KS], wfr[CFW][KS];
#pragma unroll
  for (int c = 0; c < CFW; ++c)
#pragma unroll
    for (int t = 0; t < KS; ++t) {
      int idx = ((fseg * CFW + c) * KS + t) * 64 + lane;
      wfl[c][t] = ((const bf16x8*)Wlp)[idx];
      wfr[c][t] = ((const bf16x8*)Wrp)[idx];
    }

  size_t tile0 = ((size_t)lb * NW + ng) * TILES;
  for (int it = 0; it < TILES; ++it) {
    int mb = (int)(tile0 + it) * 16;
    const bf16x8* xrow = (const bf16x8*)(xin + (size_t)(mb + l15) * FIN);
    bf16x8 bx[KS];
#pragma unroll
    for (int t = 0; t < KS; ++t) bx[t] = xrow[t * 4 + lhi];
    f32x4 accl[CFW], accr[CFW];
#pragma unroll
    for (int c = 0; c < CFW; ++c) {
      accl[c] = (f32x4){0.f, 0.f, 0.f, 0.f};
      accr[c] = (f32x4){0.f, 0.f, 0.f, 0.f};
    }
#pragma unroll
    for (int t = 0; t < KS; ++t)
#pragma unroll
      for (int c = 0; c < CFW; ++c) {
        accl[c] = __builtin_amdgcn_mfma_f32_16x16x32_bf16(wfl[c][t], bx[t], accl[c], 0, 0, 0);
        accr[c] = __builtin_amdgcn_mfma_f32_16x16x32_bf16(wfr[c][t], bx[t], accr[c], 0, 0, 0);
      }
#pragma unroll
    for (int c = 0; c < CFW; ++c) {
      int f0 = (fseg * CFW + c) * 16 + lhi * 4;
      size_t o = (size_t)(mb + l15) * FOUT + f0;
      uint2 vl; vl.x = pack_bf2(accl[c][0], accl[c][1]); vl.y = pack_bf2(accl[c][2], accl[c][3]);
      *(uint2*)(xl + o) = vl;
      uint2 vr; vr.x = pack_bf2(accr[c][0], accr[c][1]); vr.y = pack_bf2(accr[c][2], accr[c][3]);
      *(uint2*)(xr + o) = vr;
    }
  }
}

template <int FOUT>
__device__ void dev_pool(int g, const ushort* __restrict__ h,
                         const int* __restrict__ goff,
                         float* __restrict__ pooled, int colbase, int colbase2) {
  int t = threadIdx.x;
  constexpr int PAIRS = FOUT / 2;
  if (t >= PAIRS) return;
  float a0 = 0.f, a1 = 0.f;
  int b0 = goff[g], b1 = goff[g + 1];
  const uint* h32 = (const uint*)h;
  for (int n = b0; n < b1; ++n) {
    uint v = h32[(size_t)n * PAIRS + t];
    a0 += lo_bf(v);
    a1 += hi_bf(v);
  }
  pooled[g * 256 + colbase + 2 * t] = a0;
  pooled[g * 256 + colbase + 2 * t + 1] = a1;
  if (colbase2 >= 0) {
    pooled[g * 256 + colbase2 + 2 * t] = a0;
    pooled[g * 256 + colbase2 + 2 * t + 1] = a1;
  }
}

// ================= fused kernels =================

__global__ __launch_bounds__(256) void k_pre(
    const int* __restrict__ ei, int* __restrict__ counts,
    const float* __restrict__ x, ushort* __restrict__ xb,
    const float* __restrict__ Wl1, const float* __restrict__ Wr1,
    const float* __restrict__ Wl2, const float* __restrict__ Wr2,
    const float* __restrict__ Wl3, const float* __restrict__ Wr3,
    ushort* __restrict__ P1l, ushort* __restrict__ P1r,
    ushort* __restrict__ P2l, ushort* __restrict__ P2r,
    ushort* __restrict__ P3l, ushort* __restrict__ P3r,
    const int* __restrict__ batch, int* __restrict__ goff) {
  int b = blockIdx.x;
  if (b < HIST_B) dev_hist(b, ei, counts);
  else if (b < HIST_B + CVT_B) dev_cvt(b - HIST_B, x, xb);
  else if (b < HIST_B + CVT_B + PACK_B)
    dev_pack(b - HIST_B - CVT_B, Wl1, Wr1, Wl2, Wr2, Wl3, Wr3,
             P1l, P1r, P2l, P2r, P3l, P3r);
  else dev_gbound(b - HIST_B - CVT_B - PACK_B, batch, goff);
}

__global__ __launch_bounds__(256) void k_scat_gemm1(
    const int* __restrict__ ei, int* __restrict__ cursor,
    ushort* __restrict__ csr_src, const ushort* __restrict__ xb,
    const ushort* __restrict__ P1l, const ushort* __restrict__ P1r,
    ushort* __restrict__ xl, ushort* __restrict__ xr) {
  int b = blockIdx.x;
  if (b < SCAT_B) dev_scatter(b, ei, cursor, csr_src);
  else dev_gemm<128, 128, 8>(b - SCAT_B, xb, P1l, P1r, xl, xr);
}

__global__ __launch_bounds__(256) void k_pool1_gemm2(
    const ushort* __restrict__ h, const int* __restrict__ goff,
    float* __restrict__ pooled, const ushort* __restrict__ P2l,
    const ushort* __restrict__ P2r, ushort* __restrict__ xl,
    ushort* __restrict__ xr) {
  int b = blockIdx.x;
  if (b < POOL_B) dev_pool<128>(b, h, goff, pooled, 0, -1);
  else dev_gemm<128, 64, 8>(b - POOL_B, h, P2l, P2r, xl, xr);
}

__global__ __launch_bounds__(256) void k_pool2_gemm3(
    const ushort* __restrict__ h, const int* __restrict__ goff,
    float* __restrict__ pooled, const ushort* __restrict__ P3l,
    const ushort* __restrict__ P3r, ushort* __restrict__ xl,
    ushort* __restrict__ xr) {
  int b = blockIdx.x;
  if (b < POOL_B) dev_pool<64>(b, h, goff, pooled, 128, -1);
  else dev_gemm<64, 32, 8>(b - POOL_B, h, P3l, P3r, xl, xr);
}

// ================= scans =================

__global__ __launch_bounds__(256) void scan1_kernel(const int* __restrict__ counts,
                                                    int* __restrict__ bsum) {
  __shared__ int ws[4];
  int b = blockIdx.x, t = threadIdx.x;
  int4 v = ((const int4*)(counts + b * 1024))[t];
  int s = v.x + v.y + v.z + v.w;
#pragma unroll
  for (int d = 1; d < 64; d <<= 1) s += __shfl_xor(s, d);
  if ((t & 63) == 0) ws[t >> 6] = s;
  __syncthreads();
  if (t == 0) bsum[b] = ws[0] + ws[1] + ws[2] + ws[3];
}

__global__ __launch_bounds__(64) void scan2_kernel(const int* __restrict__ bsum,
                                                   int* __restrict__ boff,
                                                   int* __restrict__ off_last) {
  int t = threadIdx.x;
  int v = bsum[t];
  int s = v;
#pragma unroll
  for (int d = 1; d < 64; d <<= 1) {
    int u = __shfl_up(s, d);
    if (t >= d) s += u;
  }
  boff[t] = s - v;
  if (t == 63) *off_last = s;
}

__global__ __launch_bounds__(256) void scan3_kernel(int* __restrict__ counts,
                                                    const int* __restrict__ boff,
                                                    int* __restrict__ off) {
  __shared__ int wsum[4];
  int b = blockIdx.x, t = threadIdx.x;
  int base = b * 1024;
  int4 v = ((const int4*)(counts + base))[t];
  int s = v.x + v.y + v.z + v.w;
  int inc = s;
#pragma unroll
  for (int d = 1; d < 64; d <<= 1) {
    int u = __shfl_up(inc, d);
    if ((t & 63) >= d) inc += u;
  }
  int wave = t >> 6;
  if ((t & 63) == 63) wsum[wave] = inc;
  __syncthreads();
  int wadd = 0;
  for (int wv = 0; wv < wave; ++wv) wadd += wsum[wv];
  int ex = inc - s + wadd + boff[b];
  int4 o;
  o.x = ex; o.y = ex + v.x; o.z = o.y + v.y; o.w = o.z + v.z;
  ((int4*)(off + base))[t] = o;
  ((int4*)(counts + base))[t] = o;   // cursor copy, in place
}

// ================= edge aggregation (online segment softmax) =================

template <int FOUT>
__global__ __launch_bounds__(256) void edge_kernel(
    const ushort* __restrict__ xl, const ushort* __restrict__ xr,
    const int* __restrict__ csr_off, const ushort* __restrict__ csr_src,
    const float* __restrict__ a, const float* __restrict__ b,
    const float* __restrict__ gam, const float* __restrict__ bet,
    ushort* __restrict__ hout) {
  constexpr int GROUP = FOUT / 8;   // 16 / 8 / 4
  constexpr int GPB = 256 / GROUP;
  int gid = blockIdx.x * GPB + threadIdx.x / GROUP;
  int lane = threadIdx.x % GROUP;
  const uint4* xl4 = (const uint4*)xl;

  float xrf[8];
  cvt8(((const uint4*)xr)[gid * GROUP + lane], xrf);
  float av[8];
  {
    float4 a0 = ((const float4*)a)[lane * 2], a1 = ((const float4*)a)[lane * 2 + 1];
    av[0] = a0.x; av[1] = a0.y; av[2] = a0.z; av[3] = a0.w;
    av[4] = a1.x; av[5] = a1.y; av[6] = a1.z; av[7] = a1.w;
  }
  int beg = csr_off[gid], end = csr_off[gid + 1];

  float m = -INFINITY, den = 0.f;
  float acc[8] = {0.f, 0.f, 0.f, 0.f, 0.f, 0.f, 0.f, 0.f};
  int i = beg;
  for (; i + 4 <= end; i += 4) {
    int s0 = csr_src[i], s1 = csr_src[i + 1];
    int s2 = csr_src[i + 2], s3 = csr_src[i + 3];
    uint4 v0 = xl4[(size_t)s0 * GROUP + lane];
    uint4 v1 = xl4[(size_t)s1 * GROUP + lane];
    uint4 v2 = xl4[(size_t)s2 * GROUP + lane];
    uint4 v3 = xl4[(size_t)s3 * GROUP + lane];
    float x0[8], x1[8], x2[8], x3[8];
    cvt8(v0, x0); cvt8(v1, x1); cvt8(v2, x2); cvt8(v3, x3);
    float sc0 = 0.f, sc1 = 0.f, sc2 = 0.f, sc3 = 0.f;
#pragma unroll
    for (int j = 0; j < 8; ++j) {
      float z0 = x0[j] + xrf[j];
      float z1 = x1[j] + xrf[j];
      float z2 = x2[j] + xrf[j];
      float z3 = x3[j] + xrf[j];
      sc0 = fmaf(fmaxf(z0, 0.2f * z0), av[j], sc0);
      sc1 = fmaf(fmaxf(z1, 0.2f * z1), av[j], sc1);
      sc2 = fmaf(fmaxf(z2, 0.2f * z2), av[j], sc2);
      sc3 = fmaf(fmaxf(z3, 0.2f * z3), av[j], sc3);
    }
#pragma unroll
    for (int wd = GROUP >> 1; wd >= 1; wd >>= 1) {
      sc0 += __shfl_xor(sc0, wd);
      sc1 += __shfl_xor(sc1, wd);
      sc2 += __shfl_xor(sc2, wd);
      sc3 += __shfl_xor(sc3, wd);
    }
    float m2 = fmaxf(m, fmaxf(fmaxf(sc0, sc1), fmaxf(sc2, sc3)));
    float scale = __expf(m - m2);
    float p0 = __expf(sc0 - m2), p1 = __expf(sc1 - m2);
    float p2 = __expf(sc2 - m2), p3 = __expf(sc3 - m2);
    den = den * scale + p0 + p1 + p2 + p3;
#pragma unroll
    for (int j = 0; j < 8; ++j)
      acc[j] = fmaf(acc[j], scale,
                    fmaf(p0, x0[j], fmaf(p1, x1[j], fmaf(p2, x2[j], p3 * x3[j]))));
    m = m2;
  }
  for (; i < end; ++i) {
    int s0 = csr_src[i];
    uint4 v0 = xl4[(size_t)s0 * GROUP + lane];
    float x0[8];
    cvt8(v0, x0);
    float sc0 = 0.f;
#pragma unroll
    for (int j = 0; j < 8; ++j) {
      float z0 = x0[j] + xrf[j];
      sc0 = fmaf(fmaxf(z0, 0.2f * z0), av[j], sc0);
    }
#pragma unroll
    for (int wd = GROUP >> 1; wd >= 1; wd >>= 1) sc0 += __shfl_xor(sc0, wd);
    float m2 = fmaxf(m, sc0);
    float scale = __expf(m - m2);
    float p0 = __expf(sc0 - m2);
    den = den * scale + p0;
#pragma unroll
    for (int j = 0; j < 8; ++j) acc[j] = fmaf(acc[j], scale, p0 * x0[j]);
    m = m2;
  }
  float inv = 1.f / den;
  float4 b0 = ((const float4*)b)[lane * 2], b1 = ((const float4*)b)[lane * 2 + 1];
  float4 g0 = ((const float4*)gam)[lane * 2], g1 = ((const float4*)gam)[lane * 2 + 1];
  float4 e0 = ((const float4*)bet)[lane * 2], e1 = ((const float4*)bet)[lane * 2 + 1];
  float bb[8] = {b0.x, b0.y, b0.z, b0.w, b1.x, b1.y, b1.z, b1.w};
  float gg[8] = {g0.x, g0.y, g0.z, g0.w, g1.x, g1.y, g1.z, g1.w};
  float ee[8] = {e0.x, e0.y, e0.z, e0.w, e1.x, e1.y, e1.z, e1.w};
  float o[8];
#pragma unroll
  for (int j = 0; j < 8; ++j)
    o[j] = fmaxf(acc[j] * inv + bb[j], 0.f) * (gg[j] * BNS) + ee[j];
  uint4 pv;
  pv.x = pack_bf2(o[0], o[1]); pv.y = pack_bf2(o[2], o[3]);
  pv.z = pack_bf2(o[4], o[5]); pv.w = pack_bf2(o[6], o[7]);
  ((uint4*)hout)[gid * GROUP + lane] = pv;
}

// ================= standalone pool (layer 3) =================

template <int FOUT>
__global__ __launch_bounds__(64) void pool_kernel(const ushort* __restrict__ h,
                                                  const int* __restrict__ goff,
                                                  float* __restrict__ pooled,
                                                  int colbase, int colbase2) {
  int g = blockIdx.x;
  int t = threadIdx.x;
  constexpr int PAIRS = FOUT / 2;
  if (t >= PAIRS) return;
  float a0 = 0.f, a1 = 0.f;
  int b0 = goff[g], b1 = goff[g + 1];
  const uint* h32 = (const uint*)h;
  for (int n = b0; n < b1; ++n) {
    uint v = h32[(size_t)n * PAIRS + t];
    a0 += lo_bf(v);
    a1 += hi_bf(v);
  }
  pooled[g * 256 + colbase + 2 * t] = a0;
  pooled[g * 256 + colbase + 2 * t + 1] = a1;
  if (colbase2 >= 0) {
    pooled[g * 256 + colbase2 + 2 * t] = a0;
    pooled[g * 256 + colbase2 + 2 * t + 1] = a1;
  }
}

// ================= MLP head + outputs =================

__global__ __launch_bounds__(128) void mlp_kernel(
    const float* __restrict__ pooled, const float* __restrict__ W1,
    const float* __restrict__ b1, const float* __restrict__ g5,
    const float* __restrict__ be5, const float* __restrict__ W2,
    const float* __restrict__ b2, float* __restrict__ out) {
  __shared__ float p[256];
  __shared__ float hid[128];
  __shared__ float lg[16];
  int g = blockIdx.x, t = threadIdx.x;
  p[t] = pooled[g * 256 + t];
  p[t + 128] = pooled[g * 256 + 128 + t];
  __syncthreads();
  float acc = b1[t];
  for (int k = 0; k < 256; ++k) acc = fmaf(p[k], W1[k * 128 + t], acc);
  acc = fmaxf(acc, 0.f) * (g5[t] * BNS) + be5[t];
  hid[t] = acc;
  __syncthreads();
  if (t < 16) {
    float l = b2[t];
    for (int k = 0; k < 128; ++k) l = fmaf(hid[k], W2[k * 16 + t], l);
    lg[t] = l;
  }
  __syncthreads();
  if (t < 16) {
    float l = lg[t];
    float m = lg[0];
    for (int k = 1; k < 16; ++k) m = fmaxf(m, lg[k]);
    float se = 0.f;
    for (int k = 0; k < 16; ++k) se += __expf(lg[k] - m);
    out[g * 16 + t] = 1.f / (1.f + __expf(-l));       // sigmoid
    out[NG * 16 + g * 16 + t] = l - m - __logf(se);   // log_softmax
  }
}

// ================= launch =================

extern "C" void kernel_launch(void* const* d_in, const int* in_sizes, int n_in,
                              void* d_out, int out_size, void* d_ws, size_t ws_size,
                              hipStream_t stream) {
  const float* x = (const float*)d_in[0];
  const int* ei = (const int*)d_in[1];
  const int* batch = (const int*)d_in[2];
  const float* Wl1 = (const float*)d_in[4];
  const float* Wr1 = (const float*)d_in[5];
  const float* a1 = (const float*)d_in[6];
  const float* b1 = (const float*)d_in[7];
  const float* g1 = (const float*)d_in[8];
  const float* be1 = (const float*)d_in[9];
  const float* Wl2 = (const float*)d_in[10];
  const float* Wr2 = (const float*)d_in[11];
  const float* a2 = (const float*)d_in[12];
  const float* b2 = (const float*)d_in[13];
  const float* g2 = (const float*)d_in[14];
  const float* be2 = (const float*)d_in[15];
  const float* Wl3 = (const float*)d_in[16];
  const float* Wr3 = (const float*)d_in[17];
  const float* a3 = (const float*)d_in[18];
  const float* b3 = (const float*)d_in[19];
  const float* g3 = (const float*)d_in[20];
  const float* be3 = (const float*)d_in[21];
  // layer 4 (d_in[22..27]) is dead in the reference (h4 = h3) — skipped.
  const float* lin1_W = (const float*)d_in[28];
  const float* lin1_b = (const float*)d_in[29];
  const float* g5 = (const float*)d_in[30];
  const float* be5 = (const float*)d_in[31];
  const float* lin2_W = (const float*)d_in[32];
  const float* lin2_b = (const float*)d_in[33];
  float* out = (float*)d_out;

  // workspace carve (16B-aligned chunks)
  char* w = (char*)d_ws;
  ushort* xb = (ushort*)w;  w += (size_t)NN * 128 * 2;  // 16 MB
  ushort* xl = (ushort*)w;  w += (size_t)NN * 128 * 2;  // 16 MB
  ushort* xr = (ushort*)w;  w += (size_t)NN * 128 * 2;  // 16 MB
  ushort* h  = (ushort*)w;  w += (size_t)NN * 128 * 2;  // 16 MB
  ushort* P1l = (ushort*)w; w += 65536;
  ushort* P1r = (ushort*)w; w += 65536;
  ushort* P2l = (ushort*)w; w += 65536;
  ushort* P2r = (ushort*)w; w += 65536;
  ushort* P3l = (ushort*)w; w += 65536;
  ushort* P3r = (ushort*)w; w += 65536;
  int* counts = (int*)w;    w += (size_t)NN * 4;        // becomes scatter cursor
  int* csr_off = (int*)w;   w += (size_t)(NN + 4) * 4;
  ushort* csr_src = (ushort*)w; w += (size_t)(ET + 8) * 2;
  int* bsum = (int*)w;      w += 64 * 4;
  int* boff = (int*)w;      w += 64 * 4;
  int* goff = (int*)w;      w += (size_t)(NG + 4) * 4;
  float* pooled = (float*)w; w += (size_t)NG * 256 * 4;

  hipMemsetAsync(counts, 0, (size_t)NN * 4, stream);

  // hist | cvt | pack | gbound
  k_pre<<<PRE_B, 256, 0, stream>>>(ei, counts, x, xb, Wl1, Wr1, Wl2, Wr2,
                                   Wl3, Wr3, P1l, P1r, P2l, P2r, P3l, P3r,
                                   batch, goff);
  scan1_kernel<<<64, 256, 0, stream>>>(counts, bsum);
  scan2_kernel<<<1, 64, 0, stream>>>(bsum, boff, &csr_off[NN]);
  scan3_kernel<<<64, 256, 0, stream>>>(counts, boff, csr_off);

  // scatter | gemm layer1
  k_scat_gemm1<<<SG1_B, 256, 0, stream>>>(ei, counts, csr_src, xb, P1l, P1r,
                                          xl, xr);
  edge_kernel<128><<<NN / 16, 256, 0, stream>>>(xl, xr, csr_off, csr_src,
                                                a1, b1, g1, be1, h);

  // pool1 | gemm layer2
  k_pool1_gemm2<<<POOL_B + 512, 256, 0, stream>>>(h, goff, pooled, P2l, P2r,
                                                  xl, xr);
  edge_kernel<64><<<NN / 32, 256, 0, stream>>>(xl, xr, csr_off, csr_src,
                                               a2, b2, g2, be2, h);

  // pool2 | gemm layer3
  k_pool2_gemm3<<<POOL_B + 256, 256, 0, stream>>>(h, goff, pooled, P3l, P3r,
                                                  xl, xr);
  edge_kernel<32><<<NN / 64, 256, 0, stream>>>(xl, xr, csr_off, csr_src,
                                               a3, b3, g3, be3, h);

  pool_kernel<32><<<NG, 64, 0, stream>>>(h, goff, pooled, 192, 224);
  mlp_kernel<<<NG, 128, 0, stream>>>(pooled, lin1_W, lin1_b, g5, be5, lin2_W,
                                     lin2_b, out);
}